// Round 2
// baseline (2869.827 us; speedup 1.0000x reference)
//
#include <hip/hip_runtime.h>
#include <cstdint>
#include <cstddef>

#define N_ 46080
#define B_ 64
#define BLKG 720
#define E_ 400000
#define CX_ 128
#define CE_ 32
#define BNEPS_ 1e-5f
#define CC_ITERS_ 40
#define BITW 24   // words of presence bitmask per cluster (768 bits >= 720)

static inline int gr(int n, int b) { return (n + b - 1) / b; }

// ---------------- CSR / reverse-edge ----------------

__global__ void k_rowptr(const int* __restrict__ row, int* __restrict__ rp) {
  int n = blockIdx.x * blockDim.x + threadIdx.x;
  if (n > N_) return;
  int lo = 0, hi = E_;
  while (lo < hi) { int mid = (lo + hi) >> 1; if (row[mid] < n) lo = mid + 1; else hi = mid; }
  rp[n] = lo;
}

__global__ void k_pos(const int* __restrict__ row, const int* __restrict__ col,
                      int* __restrict__ pos) {
  int e = blockIdx.x * blockDim.x + threadIdx.x;
  if (e >= E_) return;
  long long target = (long long)col[e] * N_ + row[e];
  int lo = 0, hi = E_ - 1;
  while (lo < hi) {
    int mid = (lo + hi) >> 1;
    long long k = (long long)row[mid] * N_ + col[mid];
    if (k < target) lo = mid + 1; else hi = mid;
  }
  pos[e] = lo;
}

// tgt[n][k] = sum over edges e' with col[e']==n of attr[e'] via reverse map pos
__global__ void k_tgt(const float* __restrict__ attr, const int* __restrict__ pos,
                      const int* __restrict__ rp, float* __restrict__ tgt) {
  int t = blockIdx.x * blockDim.x + threadIdx.x;
  if (t >= N_ * CE_) return;
  int n = t / CE_, k = t % CE_;
  float s = 0.f;
  int b = rp[n], e = rp[n + 1];
  for (int i = b; i < e; i++) s += attr[(size_t)pos[i] * CE_ + k];
  tgt[t] = s;
}

__global__ void k_eaprop(const float* __restrict__ attr, const float* __restrict__ tgt,
                         const int* __restrict__ row, float* __restrict__ A) {
  int t = blockIdx.x * blockDim.x + threadIdx.x;
  if (t >= E_ * CE_) return;
  int e = t / CE_, k = t % CE_;
  A[t] = tgt[row[e] * CE_ + k] + attr[t];
}

// ---------------- mlp_e: Linear(32->32) + BN(train) + ReLU ----------------

__global__ void k_mlp(const float* __restrict__ A, const float* __restrict__ We,
                      const float* __restrict__ be, float* __restrict__ H) {
  __shared__ float sWe[CE_ * CE_];
  __shared__ float sA[8 * CE_];
  int t = threadIdx.x;
  for (int i = t; i < CE_ * CE_; i += 256) sWe[i] = We[i];
  int e0 = blockIdx.x * 8;
  for (int i = t; i < 8 * CE_; i += 256) sA[i] = A[(size_t)e0 * CE_ + i];
  __syncthreads();
  int el = t >> 5, j = t & 31;
  float acc = be[j];
  for (int k = 0; k < CE_; k++) acc += sA[el * CE_ + k] * sWe[k * CE_ + j];
  H[(size_t)(e0 + el) * CE_ + j] = acc;
}

__global__ void k_bnstats(const float* __restrict__ H, double* __restrict__ acc) {
  int t = threadIdx.x; int ch = t & 31, grp = t >> 5;
  double s = 0.0, s2 = 0.0;
  for (int e = blockIdx.x * 8 + grp; e < E_; e += gridDim.x * 8) {
    double v = H[(size_t)e * CE_ + ch];
    s += v; s2 += v * v;
  }
  __shared__ double sh[256], sh2[256];
  sh[t] = s; sh2[t] = s2; __syncthreads();
  for (int off = 128; off >= 32; off >>= 1) {
    if (t < off) { sh[t] += sh[t + off]; sh2[t] += sh2[t + off]; }
    __syncthreads();
  }
  if (t < 32) { atomicAdd(&acc[ch], sh[t]); atomicAdd(&acc[32 + ch], sh2[t]); }
}

__global__ void k_bnfin(const double* __restrict__ acc, const float* __restrict__ g,
                        const float* __restrict__ b, const float* __restrict__ S,
                        float* __restrict__ scale, float* __restrict__ shift,
                        float* __restrict__ snorm) {
  int t = threadIdx.x;
  if (t < CE_) {
    double mu = acc[t] / (double)E_;
    double var = acc[32 + t] / (double)E_ - mu * mu;
    float sc = (float)((double)g[t] / sqrt(var + 1e-5));
    scale[t] = sc;
    shift[t] = b[t] - (float)mu * sc;
  }
  if (t == 0) {
    float s = 0.f;
    for (int k = 0; k < CE_; k++) s += S[k] * S[k];
    *snorm = sqrtf(s);
  }
}

__global__ void k_bnapply(const float* __restrict__ H, const float* __restrict__ scale,
                          const float* __restrict__ shift, float* __restrict__ A) {
  int t = blockIdx.x * blockDim.x + threadIdx.x;
  if (t >= E_ * CE_) return;
  int k = t & 31;
  float v = H[t] * scale[k] + shift[k];
  A[t] = v > 0.f ? v : 0.f;
}

// ---------------- edge score / selection ----------------

__global__ void k_tdot(const float* __restrict__ A, const float* __restrict__ S,
                       float* __restrict__ tdot) {
  __shared__ float sS[CE_];
  if (threadIdx.x < CE_) sS[threadIdx.x] = S[threadIdx.x];
  __syncthreads();
  int e = blockIdx.x * blockDim.x + threadIdx.x;
  if (e >= E_) return;
  const float4* a4 = (const float4*)(A + (size_t)e * CE_);
  float s = 0.f;
  for (int q = 0; q < 8; q++) {
    float4 v = a4[q];
    s += v.x * sS[q * 4 + 0] + v.y * sS[q * 4 + 1] + v.z * sS[q * 4 + 2] + v.w * sS[q * 4 + 3];
  }
  tdot[e] = s;
}

__global__ void k_score(const float* __restrict__ tdot, const int* __restrict__ pos,
                        const float* __restrict__ snorm, float* __restrict__ score) {
  int e = blockIdx.x * blockDim.x + threadIdx.x;
  if (e >= E_) return;
  float z = (tdot[e] + tdot[pos[e]]) / (*snorm);
  score[e] = 1.f / (1.f + expf(-z));
}

__global__ void k_gmean(const float* __restrict__ score, const int* __restrict__ rp,
                        float* __restrict__ gmean) {
  int g = blockIdx.x; int t = threadIdx.x;
  int b = rp[g * BLKG], e = rp[(g + 1) * BLKG];
  float s = 0.f;
  for (int i = b + t; i < e; i += 256) s += score[i];
  __shared__ float sh[256];
  sh[t] = s; __syncthreads();
  for (int off = 128; off; off >>= 1) { if (t < off) sh[t] += sh[t + off]; __syncthreads(); }
  if (t == 0) gmean[g] = sh[0] / (float)(e - b);
}

__global__ void k_sel(const float* __restrict__ score, const float* __restrict__ gmean,
                      const int* __restrict__ row, const int* __restrict__ col,
                      int* __restrict__ sel, int* __restrict__ xmask,
                      int* __restrict__ nsel, int* __restrict__ sr, int* __restrict__ sc) {
  int e = blockIdx.x * blockDim.x + threadIdx.x;
  if (e >= E_) return;
  int r = row[e];
  int g = r / BLKG;
  float s = score[e];
  int v = (s <= 0.5f) && (s < gmean[g]);
  sel[e] = v;
  if (v) {
    atomicOr(&xmask[r], 1);
    int i = atomicAdd(nsel, 1);
    sr[i] = r; sc[i] = col[e];
  }
}

__global__ void k_ea3(float* __restrict__ A, const float* __restrict__ score) {
  int t = blockIdx.x * blockDim.x + threadIdx.x;
  if (t >= E_ * CE_) return;
  A[t] *= score[t >> 5];
}

// ---------------- connected components ----------------

__global__ void k_ccinit(int* __restrict__ lab, int* __restrict__ cura) {
  int n = blockIdx.x * blockDim.x + threadIdx.x;
  if (n < N_) { lab[n] = n; cura[n] = n; }
}

__global__ void k_cmin(const int* __restrict__ sr, const int* __restrict__ sc,
                       const int* __restrict__ lab, int* __restrict__ cur,
                       const int* __restrict__ nsel) {
  int ns = *nsel;
  for (int i = blockIdx.x * blockDim.x + threadIdx.x; i < ns; i += gridDim.x * blockDim.x) {
    int r = sr[i], c = sc[i];
    atomicMin(&cur[r], lab[c]);
    atomicMin(&cur[c], lab[r]);
  }
}

__global__ void k_cjump(const int* __restrict__ cur, int* __restrict__ lab,
                        int* __restrict__ nxt) {
  int n = blockIdx.x * blockDim.x + threadIdx.x;
  if (n >= N_) return;
  int v = cur[n]; v = cur[v]; v = cur[v]; v = cur[v];  // m[m] twice == cur^4
  lab[n] = v; nxt[n] = v;
}

__global__ void k_isrep(const int* __restrict__ lab, int* __restrict__ cum) {
  int n = blockIdx.x * blockDim.x + threadIdx.x;
  if (n < N_) cum[n] = (lab[n] == n) ? 1 : 0;
}

// single-block in-place inclusive scan
__global__ void k_scan(int* __restrict__ d, int n) {
  __shared__ int s[1024];
  __shared__ int carry;
  if (threadIdx.x == 0) carry = 0;
  __syncthreads();
  for (int base = 0; base < n; base += 1024) {
    int i = base + threadIdx.x;
    int v = (i < n) ? d[i] : 0;
    s[threadIdx.x] = v; __syncthreads();
    for (int off = 1; off < 1024; off <<= 1) {
      int t2 = (threadIdx.x >= off) ? s[threadIdx.x - off] : 0;
      __syncthreads();
      s[threadIdx.x] += t2;
      __syncthreads();
    }
    if (i < n) d[i] = s[threadIdx.x] + carry;
    __syncthreads();
    if (threadIdx.x == 0) carry += s[1023];
    __syncthreads();
  }
}

__global__ void k_crep(const int* __restrict__ cum, int* __restrict__ crep) {
  int g = threadIdx.x;
  if (g <= B_) crep[g] = (g == 0) ? 0 : cum[g * BLKG - 1];
}

__global__ void k_comp(const int* __restrict__ cum, const int* __restrict__ lab,
                       int* __restrict__ comp) {
  int n = blockIdx.x * blockDim.x + threadIdx.x;
  if (n < N_) comp[n] = cum[lab[n]] - 1;
}

__global__ void k_cnt(const int* __restrict__ comp, const int* __restrict__ batch,
                      const int* __restrict__ xmask, int* __restrict__ cnt,
                      int* __restrict__ bsum, int* __restrict__ keep) {
  int n = blockIdx.x * blockDim.x + threadIdx.x;
  if (n >= N_) return;
  int c = comp[n];
  atomicAdd(&cnt[c], 1);
  atomicAdd(&bsum[c], batch[n]);
  if (!xmask[n]) atomicAdd(&keep[c], 1);
}

// batch_out written as FLOAT values (harness reads d_out as float32)
__global__ void k_batchout(const int* __restrict__ cnt, const int* __restrict__ bsum,
                           float* __restrict__ bout) {
  int c = blockIdx.x * blockDim.x + threadIdx.x;
  if (c >= N_) return;
  int ct = cnt[c];
  bout[c] = (float)(bsum[c] / (ct > 0 ? ct : 1));
}

// ---------------- EGIN conv ----------------

__global__ void k_agg(const float* __restrict__ x, const float* __restrict__ A,
                      const int* __restrict__ col, const int* __restrict__ rp,
                      const int* __restrict__ sel, const float* __restrict__ W_edge,
                      const float* __restrict__ epsp, float* __restrict__ hc) {
  __shared__ float sW[CE_ * CX_];
  __shared__ float sea[CE_];
  int n = blockIdx.x, t = threadIdx.x;  // 128 threads
  for (int i = t; i < CE_ * CX_; i += 128) sW[i] = W_edge[i];
  float acc = 0.f;
  int b = rp[n], e = rp[n + 1];
  for (int i = b; i < e; i++) {
    if (!sel[i]) continue;  // uniform across block
    __syncthreads();
    if (t < CE_) sea[t] = A[(size_t)i * CE_ + t];
    __syncthreads();
    float m = x[(size_t)col[i] * CX_ + t];
    for (int k = 0; k < CE_; k++) m += sea[k] * sW[k * CX_ + t];
    acc += fmaxf(m, 0.f);
  }
  hc[(size_t)n * CX_ + t] = (1.f + epsp[0]) * x[(size_t)n * CX_ + t] + acc;
}

template <bool RELU>
__global__ void k_gemm128(const float* __restrict__ X, const float* __restrict__ W,
                          const float* __restrict__ bias, float* __restrict__ Y) {
  __shared__ float sX[16 * CX_];
  int t = threadIdx.x;
  int r0 = blockIdx.x * 16;
  for (int i = t; i < 16 * CX_; i += 256) sX[i] = X[(size_t)r0 * CX_ + i];
  __syncthreads();
  int j = t & 127, rl = t >> 7;
  float acc[8];
  for (int i = 0; i < 8; i++) acc[i] = 0.f;
  for (int k = 0; k < CX_; k++) {
    float w = W[k * CX_ + j];
    for (int i = 0; i < 8; i++) acc[i] += sX[(rl + 2 * i) * CX_ + k] * w;
  }
  float b = bias[j];
  for (int i = 0; i < 8; i++) {
    float v = acc[i] + b;
    if (RELU) v = fmaxf(v, 0.f);
    Y[(size_t)(r0 + rl + 2 * i) * CX_ + j] = v;
  }
}

// ---------------- pooling ----------------

__global__ void k_pool(const float* __restrict__ xc, const float* __restrict__ x,
                       const int* __restrict__ comp, const int* __restrict__ xmask,
                       float* __restrict__ poolA, float* __restrict__ poolP) {
  int t = blockIdx.x * blockDim.x + threadIdx.x;
  if (t >= N_ * CX_) return;
  int n = t >> 7, ch = t & 127;
  int c = comp[n];
  if (xmask[n]) atomicAdd(&poolA[(size_t)c * CX_ + ch], xc[t]);
  else          atomicAdd(&poolP[(size_t)c * CX_ + ch], x[t]);
}

__global__ void k_xout(const float* __restrict__ poolA, const float* __restrict__ poolP,
                       const int* __restrict__ keep, float* __restrict__ xout) {
  int t = blockIdx.x * blockDim.x + threadIdx.x;
  if (t >= N_ * CX_) return;
  int c = t >> 7;
  xout[t] = (keep[c] > 0) ? poolP[t] : poolA[t];
}

// ---------------- edge coalesce (sort-free grouping) ----------------

__global__ void k_fillm1(float* __restrict__ p, int n) {
  int t = blockIdx.x * blockDim.x + threadIdx.x;
  if (t < n) p[t] = -1.0f;
}

__global__ void k_presbits(const int* __restrict__ row, const int* __restrict__ col,
                           const int* __restrict__ sel, const int* __restrict__ comp,
                           const int* __restrict__ crep, unsigned int* __restrict__ bits) {
  int e = blockIdx.x * blockDim.x + threadIdx.x;
  if (e >= E_ || sel[e]) return;
  int cu = comp[row[e]], cv = comp[col[e]];
  int g = row[e] / BLKG;
  int j = cv - crep[g];
  atomicOr(&bits[(size_t)cu * BITW + (j >> 5)], 1u << (j & 31));
}

__global__ void k_dcount(const unsigned int* __restrict__ bits, int* __restrict__ dscan) {
  int cu = blockIdx.x * blockDim.x + threadIdx.x;
  if (cu >= N_) return;
  int s = 0;
  for (int w = 0; w < BITW; w++) s += __popc(bits[(size_t)cu * BITW + w]);
  dscan[cu] = s;
}

__global__ void k_grank(const int* __restrict__ row, const int* __restrict__ col,
                        const int* __restrict__ sel, const int* __restrict__ comp,
                        const int* __restrict__ crep, const unsigned int* __restrict__ bits,
                        const int* __restrict__ dscan, int* __restrict__ grank) {
  int e = blockIdx.x * blockDim.x + threadIdx.x;
  if (e >= E_) return;
  if (sel[e]) { grank[e] = -1; return; }
  int cu = comp[row[e]], cv = comp[col[e]];
  int g = row[e] / BLKG;
  int j = cv - crep[g];
  int base = (cu > 0) ? dscan[cu - 1] : 0;
  int r = 0, wj = j >> 5;
  for (int w = 0; w < wj; w++) r += __popc(bits[(size_t)cu * BITW + w]);
  unsigned int mask = (1u << (j & 31)) - 1u;
  r += __popc(bits[(size_t)cu * BITW + wj] & mask);
  grank[e] = base + r;
}

__global__ void k_attr(const float* __restrict__ A, const int* __restrict__ grank,
                       float* __restrict__ attr_out) {
  int t = blockIdx.x * blockDim.x + threadIdx.x;
  if (t >= E_ * CE_) return;
  int e = t >> 5;
  int s = grank[e];
  if (s >= 0) atomicAdd(&attr_out[(size_t)s * CE_ + (t & 31)], A[t]);
}

// edge_index_out written as FLOAT values
__global__ void k_eidx(const unsigned int* __restrict__ bits, const int* __restrict__ dscan,
                       const int* __restrict__ cnt, const int* __restrict__ bsum,
                       const int* __restrict__ crep, float* __restrict__ ei0,
                       float* __restrict__ ei1) {
  int cu = blockIdx.x * blockDim.x + threadIdx.x;
  if (cu >= N_) return;
  int base = (cu > 0) ? dscan[cu - 1] : 0;
  int ct = cnt[cu];
  int g = bsum[cu] / (ct > 0 ? ct : 1);
  int cb = crep[g];
  int r = 0;
  for (int w = 0; w < BITW; w++) {
    unsigned int word = bits[(size_t)cu * BITW + w];
    while (word) {
      int bitj = __ffs(word) - 1;
      int j = w * 32 + bitj;
      ei0[base + r] = (float)cu;
      ei1[base + r] = (float)(cb + j);
      r++;
      word &= word - 1;
    }
  }
}

// ---------------- global pool + BN ----------------

__global__ void k_xg(const float* __restrict__ xout, const int* __restrict__ crep,
                     float* __restrict__ xg_raw) {
  int b = blockIdx.x, ch = threadIdx.x;
  float s = 0.f;
  int c0 = crep[b], c1 = crep[b + 1];
  for (int c = c0; c < c1; c++) s += xout[(size_t)c * CX_ + ch];
  xg_raw[b * CX_ + ch] = s;
}

__global__ void k_xgbn(const float* __restrict__ xg_raw, const float* __restrict__ g,
                       const float* __restrict__ bb, float* __restrict__ xg) {
  int ch = threadIdx.x;
  float mu = 0.f;
  for (int b = 0; b < B_; b++) mu += xg_raw[b * CX_ + ch];
  mu /= (float)B_;
  float var = 0.f;
  for (int b = 0; b < B_; b++) { float d = xg_raw[b * CX_ + ch] - mu; var += d * d; }
  var /= (float)B_;
  float sc = g[ch] / sqrtf(var + BNEPS_);
  for (int b = 0; b < B_; b++)
    xg[b * CX_ + ch] = (xg_raw[b * CX_ + ch] - mu) * sc + bb[ch];
}

// ---------------- launch ----------------

extern "C" void kernel_launch(void* const* d_in, const int* in_sizes, int n_in,
                              void* d_out, int out_size, void* d_ws, size_t ws_size,
                              hipStream_t stream) {
  const float* x      = (const float*)d_in[0];
  const int*   ei     = (const int*)d_in[1];
  const int*   row    = ei;
  const int*   col    = ei + E_;
  const float* eattr  = (const float*)d_in[2];
  const int*   batch  = (const int*)d_in[3];
  const float* S      = (const float*)d_in[4];
  const float* We     = (const float*)d_in[5];
  const float* be     = (const float*)d_in[6];
  const float* bn_e_g = (const float*)d_in[7];
  const float* bn_e_b = (const float*)d_in[8];
  const float* W_edge = (const float*)d_in[9];
  const float* epsp   = (const float*)d_in[10];
  const float* W1     = (const float*)d_in[11];
  const float* b1     = (const float*)d_in[12];
  const float* W2     = (const float*)d_in[13];
  const float* b2     = (const float*)d_in[14];
  const float* bn_g   = (const float*)d_in[15];
  const float* bn_b   = (const float*)d_in[16];

  // outputs (all read back as float32)
  float* xout     = (float*)d_out;
  float* ei0      = (float*)d_out + (size_t)N_ * CX_;
  float* ei1      = ei0 + E_;
  float* attr_out = (float*)d_out + (size_t)N_ * CX_ + 2 * (size_t)E_;
  float* bout     = (float*)d_out + (size_t)N_ * CX_ + 2 * (size_t)E_ + (size_t)E_ * CE_;
  float* xg       = (float*)d_out + (size_t)N_ * CX_ + 2 * (size_t)E_ + (size_t)E_ * CE_ + N_;

  char* w = (char*)d_ws;
  size_t off = 0;
  auto alloc = [&](size_t bytes) -> void* {
    void* p = w + off;
    off += (bytes + 511) & ~(size_t)511;
    return p;
  };
  double* bnacc = (double*)alloc(64 * 8);
  float* A      = (float*)alloc((size_t)E_ * CE_ * 4);
  float* Hb     = (float*)alloc((size_t)E_ * CE_ * 4);
  float* tgt    = (float*)alloc((size_t)N_ * CE_ * 4);
  float* hc     = (float*)alloc((size_t)N_ * CX_ * 4);
  float* h1     = (float*)alloc((size_t)N_ * CX_ * 4);
  int*   pos    = (int*)alloc((size_t)E_ * 4);   // later reused as grank
  float* tdot   = (float*)alloc((size_t)E_ * 4);
  float* score  = (float*)alloc((size_t)E_ * 4);
  int*   sel    = (int*)alloc((size_t)E_ * 4);
  int*   sr     = (int*)alloc((size_t)E_ * 4);
  int*   sc     = (int*)alloc((size_t)E_ * 4);
  int*   rp     = (int*)alloc((size_t)(N_ + 1) * 4);
  int*   cum    = (int*)alloc((size_t)N_ * 4);
  int*   comp   = (int*)alloc((size_t)N_ * 4);
  int*   lab    = (int*)alloc((size_t)N_ * 4);
  int*   ca     = (int*)alloc((size_t)N_ * 4);
  int*   cb     = (int*)alloc((size_t)N_ * 4);
  int*   cnt    = (int*)alloc((size_t)N_ * 4);
  int*   bsum   = (int*)alloc((size_t)N_ * 4);
  int*   keep   = (int*)alloc((size_t)N_ * 4);
  int*   xmask  = (int*)alloc((size_t)N_ * 4);
  int*   dscan  = (int*)alloc((size_t)N_ * 4);
  unsigned int* bits = (unsigned int*)alloc((size_t)N_ * BITW * 4);
  int*   crep   = (int*)alloc((size_t)(B_ + 1) * 4);
  float* gmean  = (float*)alloc((size_t)B_ * 4);
  float* xg_raw = (float*)alloc((size_t)B_ * CX_ * 4);
  float* scale  = (float*)alloc(CE_ * 4);
  float* shift  = (float*)alloc(CE_ * 4);
  float* snorm  = (float*)alloc(4);
  int*   nsel   = (int*)alloc(4);
  if (off > ws_size) return;

  float* poolA = Hb;                       // reuse Hb after BN apply
  float* poolP = Hb + (size_t)N_ * CX_;

  // ---- zero/init ----
  hipMemsetAsync(bnacc, 0, 64 * 8, stream);
  hipMemsetAsync(cnt, 0, (size_t)N_ * 4, stream);
  hipMemsetAsync(bsum, 0, (size_t)N_ * 4, stream);
  hipMemsetAsync(keep, 0, (size_t)N_ * 4, stream);
  hipMemsetAsync(xmask, 0, (size_t)N_ * 4, stream);
  hipMemsetAsync(bits, 0, (size_t)N_ * BITW * 4, stream);
  hipMemsetAsync(nsel, 0, 4, stream);
  hipMemsetAsync(attr_out, 0, (size_t)E_ * CE_ * 4, stream);
  k_fillm1<<<gr(2 * E_, 256), 256, 0, stream>>>(ei0, 2 * E_);

  // ---- pipeline ----
  k_rowptr<<<gr(N_ + 1, 256), 256, 0, stream>>>(row, rp);
  k_pos<<<gr(E_, 256), 256, 0, stream>>>(row, col, pos);
  k_tgt<<<gr(N_ * CE_, 256), 256, 0, stream>>>(eattr, pos, rp, tgt);
  k_eaprop<<<gr(E_ * CE_, 256), 256, 0, stream>>>(eattr, tgt, row, A);

  k_mlp<<<E_ / 8, 256, 0, stream>>>(A, We, be, Hb);
  k_bnstats<<<512, 256, 0, stream>>>(Hb, bnacc);
  k_bnfin<<<1, 64, 0, stream>>>(bnacc, bn_e_g, bn_e_b, S, scale, shift, snorm);
  k_bnapply<<<gr(E_ * CE_, 256), 256, 0, stream>>>(Hb, scale, shift, A);

  k_tdot<<<gr(E_, 256), 256, 0, stream>>>(A, S, tdot);
  k_score<<<gr(E_, 256), 256, 0, stream>>>(tdot, pos, snorm, score);
  k_gmean<<<B_, 256, 0, stream>>>(score, rp, gmean);
  k_sel<<<gr(E_, 256), 256, 0, stream>>>(score, gmean, row, col, sel, xmask, nsel, sr, sc);
  k_ea3<<<gr(E_ * CE_, 256), 256, 0, stream>>>(A, score);

  // connected components
  k_ccinit<<<gr(N_, 256), 256, 0, stream>>>(lab, ca);
  {
    int* cur = ca; int* nxt = cb;
    for (int it = 0; it < CC_ITERS_; ++it) {
      k_cmin<<<512, 256, 0, stream>>>(sr, sc, lab, cur, nsel);
      k_cjump<<<gr(N_, 256), 256, 0, stream>>>(cur, lab, nxt);
      int* t = cur; cur = nxt; nxt = t;
    }
  }
  k_isrep<<<gr(N_, 256), 256, 0, stream>>>(lab, cum);
  k_scan<<<1, 1024, 0, stream>>>(cum, N_);
  k_crep<<<1, 128, 0, stream>>>(cum, crep);
  k_comp<<<gr(N_, 256), 256, 0, stream>>>(cum, lab, comp);
  k_cnt<<<gr(N_, 256), 256, 0, stream>>>(comp, batch, xmask, cnt, bsum, keep);
  k_batchout<<<gr(N_, 256), 256, 0, stream>>>(cnt, bsum, bout);

  // EGIN conv
  k_agg<<<N_, 128, 0, stream>>>(x, A, col, rp, sel, W_edge, epsp, hc);
  k_gemm128<true><<<N_ / 16, 256, 0, stream>>>(hc, W1, b1, h1);
  k_gemm128<false><<<N_ / 16, 256, 0, stream>>>(h1, W2, b2, hc);  // hc = x_conv

  // pooling (Hb dead -> poolA/poolP)
  hipMemsetAsync(Hb, 0, (size_t)2 * N_ * CX_ * 4, stream);
  k_pool<<<gr(N_ * CX_, 256), 256, 0, stream>>>(hc, x, comp, xmask, poolA, poolP);
  k_xout<<<gr(N_ * CX_, 256), 256, 0, stream>>>(poolA, poolP, keep, xout);

  // edge coalesce
  k_presbits<<<gr(E_, 256), 256, 0, stream>>>(row, col, sel, comp, crep, bits);
  k_dcount<<<gr(N_, 256), 256, 0, stream>>>(bits, dscan);
  k_scan<<<1, 1024, 0, stream>>>(dscan, N_);
  k_grank<<<gr(E_, 256), 256, 0, stream>>>(row, col, sel, comp, crep, bits, dscan, pos);
  k_attr<<<gr(E_ * CE_, 256), 256, 0, stream>>>(A, pos, attr_out);
  k_eidx<<<gr(N_, 256), 256, 0, stream>>>(bits, dscan, cnt, bsum, crep, ei0, ei1);

  // global pool + BN
  k_xg<<<B_, CX_, 0, stream>>>(xout, crep, xg_raw);
  k_xgbn<<<1, CX_, 0, stream>>>(xg_raw, bn_g, bn_b, xg);
}